// Round 6
// baseline (105.128 us; speedup 1.0000x reference)
//
#include <hip/hip_runtime.h>

// PlaceCellNetwork forward: out = softmax(tanh([x,1] @ Wh^T + bh + prev @ Wf) @ Wo^T + bo)
// B=4M, IN=2, HID=20, OUT=10.
//
// R6: R2-R5 pinned at ~95-100us across VALU rewrites (busy 62->35%) and a
// dense-coalescing rewrite -> neither VALU nor access pattern binds. All
// pipes model at <=40us; suspect is latency exposure under barrier lockstep
// + serialized scalar-load (lgkm) chains. This round:
//  - ZERO barriers: each wave stages its OWN 128-row prev slab into a
//    private LDS region and reads back only its own writes (wave-synchronous;
//    hardware lgkmcnt ordering within a wave suffices). 28 waves/CU free-run.
//  - weights NON-duplicated (24 floats/hidden unit): half the SMEM bytes,
//    s_loads coalesce to dwordx8; FMAs take the weight as SGPR operand
//    (free) or op_sel broadcast in packed form.
//  - no PINs, no output LDS restage (R5 proved store pattern irrelevant);
//    direct f32x2 stores. a-chain split into 3 partial sums for ILP.
//
// Algebra folded at repack (verified absmax 2e-3 since R3):
//   a'' = 2*log2e*(Wh x + bh + Wf^T prev);  r = rcp(1+2^a'')
//   l'  = log2e*(bo+rowsum(Wo)) - 2*log2e*Wo . r ;  out = 2^l' / sum(2^l')
//   (|l'| < ~12 -> exp2 cannot overflow -> softmax max-pass dropped)

#define HID 20
#define OUT 10
#define RPW 128                 // rows per wave
#define WPB 4                   // waves per block
#define RPB (RPW * WPB)         // 512 rows per block
#define PSTR 11                 // LDS row stride (odd -> 2-way max = free)
#define SLAB (RPW * PSTR)       // 1408 words per wave slab

typedef float f32x2 __attribute__((ext_vector_type(2)));

__device__ __forceinline__ float fast_rcp(float x) { return __builtin_amdgcn_rcpf(x); }
__device__ __forceinline__ float fast_exp2(float x) { return __builtin_amdgcn_exp2f(x); }
__device__ __forceinline__ f32x2 sp(float s) { return (f32x2){s, s}; }

#define EACH10(F) F(0) F(1) F(2) F(3) F(4) F(5) F(6) F(7) F(8) F(9)

// ---- weight repack: scalar (non-duplicated) layout ----
// per-i block of 24 floats at ws[24*i]:
//   [0]=S*Wh[i][0] [1]=S*Wh[i][1] [2]=S*(Wh[i][2]+bh[i]) [3]=pad
//   [4+o]=S*Wf[o][i]   [14+o]=-S*Wo[o][i]
// ws[480+o] = L*(bo[o]+sum_i Wo[o][i]) ;  S=2*log2e, L=log2e
__global__ void repack_kernel(const float* __restrict__ Wh, const float* __restrict__ bh,
                              const float* __restrict__ Wo, const float* __restrict__ bo,
                              const float* __restrict__ Wf, float* __restrict__ ws) {
    const float S = 2.8853900817779268f;  // 2*log2(e)
    const float L = 1.4426950408889634f;  // log2(e)
    int t = threadIdx.x;
    if (t < HID) {
        float* b = ws + 24 * t;
        b[0] = S * Wh[3 * t + 0];
        b[1] = S * Wh[3 * t + 1];
        b[2] = S * (Wh[3 * t + 2] + bh[t]);
        b[3] = 0.0f;
        for (int o = 0; o < OUT; ++o) {
            b[4 + o]  = S * Wf[o * HID + t];
            b[14 + o] = -S * Wo[o * HID + t];
        }
    } else if (t < HID + OUT) {
        int o = t - HID;
        float s = bo[o];
        for (int i = 0; i < HID; ++i) s += Wo[o * HID + i];
        ws[480 + o] = L * s;
    }
}

// ---- main kernel: barrier-free, wave-private LDS slabs, 2 rows/thread ----
__global__ __launch_bounds__(256, 4) void pcn_kernel(
    const float* __restrict__ x, const float* __restrict__ prev,
    const float* __restrict__ w, float* __restrict__ out, long B) {
    __shared__ float lds[WPB * SLAB];    // 22528 B -> 7 blocks/CU
    const int t = threadIdx.x;
    const int wv = t >> 6;
    const int l = t & 63;
    const long rw = (long)blockIdx.x * RPB + (long)RPW * wv;  // wave's first row
    float* slab = lds + SLAB * wv;

    // ---- stage this wave's 128-row prev slab: 5 dense float4 per lane ----
    {
        const long f4w = rw * OUT / 4;            // rw*10 divisible by 4
        const long lim4 = (B * OUT) >> 2;
        const float4* src = reinterpret_cast<const float4*>(prev) + f4w;
#pragma unroll
        for (int k = 0; k < 5; ++k) {
            const int idx = l + 64 * k;
            if (f4w + idx < lim4) {
                const float4 v = src[idx];
                const float vv[4] = {v.x, v.y, v.z, v.w};
                const int f0 = 4 * idx;
#pragma unroll
                for (int j = 0; j < 4; ++j) {
                    const int f = f0 + j;
                    const int r = f / OUT;         // magic-mul (f < 5120)
                    slab[PSTR * r + (f - OUT * r)] = vv[j];
                }
            }
        }
    }
    __builtin_amdgcn_wave_barrier();   // compile-time order fence (no inst)

    const bool aok = (rw + l) < B;          // wave-uniform for B%128==0
    const bool bok = (rw + 64 + l) < B;

    // ---- x: dense 8B loads ----
    f32x2 x0, x1;
    {
        f32x2 xa = {0.0f, 0.0f}, xb = {0.0f, 0.0f};
        if (aok) xa = *reinterpret_cast<const f32x2*>(x + 2 * (rw + l));
        if (bok) xb = *reinterpret_cast<const f32x2*>(x + 2 * (rw + 64 + l));
        x0 = (f32x2){xa.x, xb.x};
        x1 = (f32x2){xa.y, xb.y};
    }

    // ---- prev rows from own slab (2-way bank alias = free) ----
    const float* ra = slab + PSTR * l;
    const float* rb = slab + PSTR * (l + 64);
#define DECLP(o) f32x2 p##o = {ra[o], rb[o]};
    EACH10(DECLP)
#undef DECLP

    // ---- logit accumulators (exp2 domain) ----
#define INITL(o) f32x2 l##o = sp(w[480 + o]);
    EACH10(INITL)
#undef INITL

    // ---- stream hidden units ----
#pragma unroll
    for (int i = 0; i < HID; ++i) {
        const float* wb = w + 24 * i;
        f32x2 a0 = sp(wb[2]);
        a0 += sp(wb[0]) * x0;
        a0 += sp(wb[1]) * x1;
        a0 += sp(wb[4]) * p0;
        a0 += sp(wb[5]) * p1;
        a0 += sp(wb[6]) * p2;
        f32x2 a1 = sp(wb[7]) * p3;
        a1 += sp(wb[8]) * p4;
        a1 += sp(wb[9]) * p5;
        a1 += sp(wb[10]) * p6;
        f32x2 a2 = sp(wb[11]) * p7;
        a2 += sp(wb[12]) * p8;
        a2 += sp(wb[13]) * p9;
        const f32x2 a = (a0 + a1) + a2;
        f32x2 r;
        r.x = fast_rcp(1.0f + fast_exp2(a.x));
        r.y = fast_rcp(1.0f + fast_exp2(a.y));
#define LO(o) l##o += sp(wb[14 + o]) * r;
        EACH10(LO)
#undef LO
    }

    // ---- softmax (exp2 domain, no max pass needed) ----
#define EX(o) l##o.x = fast_exp2(l##o.x); l##o.y = fast_exp2(l##o.y);
    EACH10(EX)
#undef EX
    const f32x2 s = ((l0 + l1) + (l2 + l3)) + (((l4 + l5) + (l6 + l7)) + (l8 + l9));
    f32x2 rs;
    rs.x = fast_rcp(s.x);
    rs.y = fast_rcp(s.y);
#define SC(o) l##o *= rs;
    EACH10(SC)
#undef SC

    // ---- direct stores: 5x f32x2 per row (8B aligned) ----
    if (aok) {
        f32x2* d = reinterpret_cast<f32x2*>(out + 10 * (rw + l));
        d[0] = (f32x2){l0.x, l1.x};
        d[1] = (f32x2){l2.x, l3.x};
        d[2] = (f32x2){l4.x, l5.x};
        d[3] = (f32x2){l6.x, l7.x};
        d[4] = (f32x2){l8.x, l9.x};
    }
    if (bok) {
        f32x2* d = reinterpret_cast<f32x2*>(out + 10 * (rw + 64 + l));
        d[0] = (f32x2){l0.y, l1.y};
        d[1] = (f32x2){l2.y, l3.y};
        d[2] = (f32x2){l4.y, l5.y};
        d[3] = (f32x2){l6.y, l7.y};
        d[4] = (f32x2){l8.y, l9.y};
    }
}

// ---- fallback (no workspace): 1 row/thread ----
__global__ __launch_bounds__(256) void pcn_fallback(
    const float* __restrict__ x, const float* __restrict__ prev,
    const float* __restrict__ Wh, const float* __restrict__ bh,
    const float* __restrict__ Wo, const float* __restrict__ bo,
    const float* __restrict__ Wf, float* __restrict__ out, long B) {
    const long r = (long)blockIdx.x * blockDim.x + threadIdx.x;
    if (r >= B) return;
    const float x0 = x[2 * r], x1 = x[2 * r + 1];
#define DECLP(o) float p##o = prev[10 * r + o];
    EACH10(DECLP)
#undef DECLP
#define DECLL(o) float l##o = bo[o];
    EACH10(DECLL)
#undef DECLL
#pragma unroll
    for (int i = 0; i < HID; ++i) {
        float a = fmaf(Wh[3 * i], x0, fmaf(Wh[3 * i + 1], x1, Wh[3 * i + 2] + bh[i]));
#define FB(o) a = fmaf(Wf[o * HID + i], p##o, a);
        EACH10(FB)
#undef FB
        const float h = 1.0f - 2.0f * fast_rcp(1.0f + __expf(2.0f * a));
#define LO(o) l##o = fmaf(Wo[o * HID + i], h, l##o);
        EACH10(LO)
#undef LO
    }
    float m = l0;
#define MX(o) m = fmaxf(m, l##o);
    MX(1) MX(2) MX(3) MX(4) MX(5) MX(6) MX(7) MX(8) MX(9)
#undef MX
    float s = 0.0f;
#define EX(o) l##o = __expf(l##o - m); s += l##o;
    EACH10(EX)
#undef EX
    const float rs = fast_rcp(s);
#define ST(o) out[10 * r + o] = l##o * rs;
    EACH10(ST)
#undef ST
}

extern "C" void kernel_launch(void* const* d_in, const int* in_sizes, int n_in,
                              void* d_out, int out_size, void* d_ws, size_t ws_size,
                              hipStream_t stream) {
    const float* x    = (const float*)d_in[0];
    const float* prev = (const float*)d_in[1];
    const float* Wh   = (const float*)d_in[2];
    const float* bh   = (const float*)d_in[3];
    const float* Wo   = (const float*)d_in[4];
    const float* bo   = (const float*)d_in[5];
    const float* Wf   = (const float*)d_in[6];
    float* out = (float*)d_out;

    const long B = in_sizes[0] / 2;

    if (ws_size >= 490 * sizeof(float)) {
        float* ws = (float*)d_ws;
        repack_kernel<<<1, 64, 0, stream>>>(Wh, bh, Wo, bo, Wf, ws);
        const int grid = (int)((B + RPB - 1) / RPB);
        pcn_kernel<<<grid, 256, 0, stream>>>(x, prev, ws, out, B);
    } else {
        const int block = 256;
        const int grid = (int)((B + block - 1) / block);
        pcn_fallback<<<grid, block, 0, stream>>>(x, prev, Wh, bh, Wo, bo, Wf, out, B);
    }
}